// Round 17
// baseline (712.615 us; speedup 1.0000x reference)
//
#include <hip/hip_runtime.h>

typedef _Float16 half4 __attribute__((ext_vector_type(4)));
typedef _Float16 half8 __attribute__((ext_vector_type(8), aligned(8)));
typedef _Float16 half8a __attribute__((ext_vector_type(8), aligned(16)));

static __device__ __forceinline__ half4 to_h4(float4 v) {
    half4 h; h.x = (_Float16)v.x; h.y = (_Float16)v.y; h.z = (_Float16)v.z; h.w = (_Float16)v.w; return h;
}
static __device__ __forceinline__ float4 to_f4(half4 h) {
    return make_float4((float)h.x, (float)h.y, (float)h.z, (float)h.w);
}
static __device__ __forceinline__ half4 h4splat(float v) {
    _Float16 h = (_Float16)v; half4 r = { h, h, h, h }; return r;
}

// ---------------- helpers ----------------
static __device__ __forceinline__ float reflectf(float coord, float m) {
    float period = 2.0f * m;
    float c = fmodf(fabsf(coord), period);
    c = (c > m) ? (period - c) : c;
    return fminf(fmaxf(c, 0.0f), m);
}

// ---------------- k_wt01: fused Haar DWT levels 0+1, with k_prep folded in ----------------
__global__ __launch_bounds__(256) void k_wt01(
    const float* __restrict__ x, half4* __restrict__ tag0v, half4* __restrict__ tag1v,
    const float* __restrict__ offw0, const float* __restrict__ offb0,
    const float* __restrict__ offw1, const float* __restrict__ offb1,
    float* __restrict__ avgw, float* __restrict__ avgb) {
    int id = blockIdx.x * 256 + threadIdx.x;
    if (id < 2 * 2 * 2304) {
        int l = id / 4608;
        int rem = id % 4608;
        int d = rem / 2304;
        int r = rem % 2304;
        const float* w = l ? offw1 : offw0;
        float s = w[(d * 3 + 0) * 2304 + r] + w[(d * 3 + 1) * 2304 + r] + w[(d * 3 + 2) * 2304 + r];
        avgw[id] = s * (1.0f / 3.0f);
        if (id == 0) {
            avgb[0] = (offb0[0] + offb0[1] + offb0[2]) * (1.0f / 3.0f);
            avgb[1] = (offb0[3] + offb0[4] + offb0[5]) * (1.0f / 3.0f);
            avgb[2] = (offb1[0] + offb1[1] + offb1[2]) * (1.0f / 3.0f);
            avgb[3] = (offb1[3] + offb1[4] + offb1[5]) * (1.0f / 3.0f);
        }
    }
    if (id >= 16 * 64 * 32 * 32) return;
    int j1 = id & 31; int t = id >> 5;
    int i1 = t & 31; t >>= 5;
    int c = t & 63; int b = t >> 6;
    const float* p = x + ((long)(b * 64 + c) * 128 + 4 * i1) * 128 + 4 * j1;
    float4 r0 = *(const float4*)p;
    float4 r1 = *(const float4*)(p + 128);
    float4 r2 = *(const float4*)(p + 256);
    float4 r3 = *(const float4*)(p + 384);
    #define HAAR(a0,a1,a2,a3) make_float4(0.5f*((a0)+(a1)+(a2)+(a3)), 0.5f*((a0)+(a1)-(a2)-(a3)), \
                                          0.5f*((a0)-(a1)+(a2)-(a3)), 0.5f*((a0)-(a1)-(a2)+(a3)))
    float4 t00 = HAAR(r0.x, r0.y, r1.x, r1.y);
    float4 t01 = HAAR(r0.z, r0.w, r1.z, r1.w);
    float4 t10 = HAAR(r2.x, r2.y, r3.x, r3.y);
    float4 t11 = HAAR(r2.z, r2.w, r3.z, r3.w);
    long pbase = (long)(b * 64 + c) * 4096;
    int i0 = 2 * i1, j0 = 2 * j1;
    half4 h00 = to_h4(t00), h01 = to_h4(t01), h10 = to_h4(t10), h11 = to_h4(t11);
    half8a row0 = { h00.x, h00.y, h00.z, h00.w, h01.x, h01.y, h01.z, h01.w };
    half8a row1 = { h10.x, h10.y, h10.z, h10.w, h11.x, h11.y, h11.z, h11.w };
    *(half8a*)&tag0v[pbase + (long)i0 * 64 + j0]       = row0;
    *(half8a*)&tag0v[pbase + (long)(i0 + 1) * 64 + j0] = row1;
    tag1v[(long)(b * 64 + c) * 1024 + (long)i1 * 32 + j1] = to_h4(HAAR(t00.x, t01.x, t10.x, t11.x));
    #undef HAAR
}

// ---------------- k_off_part_both: LDS-staged tile conv, both levels ----------------
__global__ __launch_bounds__(256) void k_off_part_both(
    const half4* __restrict__ tag0, const half4* __restrict__ tag1,
    const float* __restrict__ avgw,
    _Float16* __restrict__ part0, _Float16* __restrict__ part1) {
    int bx = blockIdx.x;
    const half4* tagv; _Float16* part; int level, hh, ww, tilesX;
    if (bx < 16) { tagv = tag0; part = part0; level = 0; hh = 64; ww = 64; tilesX = 4; }
    else { bx -= 16; tagv = tag1; part = part1; level = 1; hh = 32; ww = 32; tilesX = 2; }
    int chunk = blockIdx.y;
    int b = blockIdx.z;
    int npix = hh * ww;
    int totpix = 16 * npix;
    int i0 = (bx / tilesX) * 16, j0 = (bx % tilesX) * 16;
    __shared__ half4 s[4][18][19];
    __shared__ float wls[2][4][9][4];
    int tid = threadIdx.x;
    const float* wsrc = avgw + level * 4608;
    for (int t = tid; t < 288; t += 256) {
        int d = t / 144, rem = t % 144;
        int gg = rem / 36; int tap = (rem % 36) / 4; int cc = rem & 3;
        wls[d][gg][tap][cc] = wsrc[d * 2304 + (chunk * 16 + gg * 4 + cc) * 9 + tap];
    }
    const half4 zh = { (_Float16)0, (_Float16)0, (_Float16)0, (_Float16)0 };
    for (int p = tid; p < 324; p += 256) {
        int ty = p / 18, tx = p % 18;
        int y = i0 - 1 + ty, xg = j0 - 1 + tx;
        bool ok = (unsigned)y < (unsigned)hh && (unsigned)xg < (unsigned)ww;
        #pragma unroll
        for (int gg = 0; gg < 4; gg++) {
            const half4* pg = tagv + ((long)b * 64 + chunk * 4 + gg) * npix;
            s[gg][ty][tx] = ok ? pg[y * ww + xg] : zh;
        }
    }
    __syncthreads();
    int ti = tid >> 4, tj = tid & 15;
    float ax = 0.f, ay = 0.f;
    #pragma unroll
    for (int gg = 0; gg < 4; gg++) {
        #pragma unroll
        for (int di = 0; di < 3; di++) {
            #pragma unroll
            for (int dj = 0; dj < 3; dj++) {
                float4 v = to_f4(s[gg][ti + di][tj + dj]);
                const float* wx = &wls[0][gg][di * 3 + dj][0];
                const float* wy = &wls[1][gg][di * 3 + dj][0];
                ax = fmaf(v.x, wx[0], ax); ax = fmaf(v.y, wx[1], ax);
                ax = fmaf(v.z, wx[2], ax); ax = fmaf(v.w, wx[3], ax);
                ay = fmaf(v.x, wy[0], ay); ay = fmaf(v.y, wy[1], ay);
                ay = fmaf(v.z, wy[2], ay); ay = fmaf(v.w, wy[3], ay);
            }
        }
    }
    long pid = (long)b * npix + (long)(i0 + ti) * ww + (j0 + tj);
    part[(long)chunk * totpix + pid]        = (_Float16)ax;
    part[((long)16 + chunk) * totpix + pid] = (_Float16)ay;
}

// ---------------- k_off_red_both ----------------
__global__ __launch_bounds__(256) void k_off_red_both(
    const _Float16* __restrict__ part0, const _Float16* __restrict__ part1,
    const float* __restrict__ avgb,
    float* __restrict__ ox0, float* __restrict__ oy0,
    float* __restrict__ ox1, float* __restrict__ oy1) {
    int bx = blockIdx.x;
    const _Float16* part; float* ox; float* oy; int level, totpix;
    if (bx < 256) { part = part0; ox = ox0; oy = oy0; level = 0; totpix = 65536; }
    else          { bx -= 256; part = part1; ox = ox1; oy = oy1; level = 1; totpix = 16384; }
    int id = bx * 256 + threadIdx.x;
    if (id >= totpix) return;
    float sx = avgb[level * 2 + 0], sy = avgb[level * 2 + 1];
    #pragma unroll
    for (int c = 0; c < 16; c++) sx += (float)part[(long)c * totpix + id];
    #pragma unroll
    for (int c = 0; c < 16; c++) sy += (float)part[((long)16 + c) * totpix + id];
    ox[id] = sx; oy[id] = sy;
}

// ---------------- k_snake (level 1): packed-fp16 sbuf/bilinear/conv (gather) ----------------
template<int GPB>
__global__ __launch_bounds__(256, 4) void k_snake(
    const half4* __restrict__ tagv,
    const float* __restrict__ ox, const float* __restrict__ oy,
    const float* __restrict__ dww, const float* __restrict__ pww,
    const float* __restrict__ wsc,
    half4* __restrict__ outv, int B, int hh, int ww) {
    __shared__ half4 sbuf[2][18][19];
    __shared__ half4 dwWh[GPB][9];
    __shared__ float pwW[GPB][16];
    __shared__ float wscW[GPB][4];
    int tilesX = ww >> 4;
    int tile = blockIdx.x;
    int g0 = blockIdx.y * GPB;
    int bz = blockIdx.z;
    int i0 = (tile / tilesX) * 16;
    int j0 = (tile % tilesX) * 16;
    int tid = threadIdx.x;
    for (int t = tid; t < GPB * 36; t += 256) {
        int gg = t / 36, rem = t % 36, cc = rem / 9, tap = rem % 9;
        ((_Float16*)&dwWh[gg][tap])[cc] = (_Float16)dww[g0 * 36 + t];
    }
    for (int t = tid; t < GPB * 16; t += 256) pwW[t / 16][t % 16] = pww[g0 * 16 + t];
    for (int t = tid; t < GPB * 4;  t += 256) wscW[t / 4][t % 4]  = wsc[g0 * 4 + t];
    int npix = hh * ww;
    const float* oxb = ox + (long)bz * npix;
    const float* oyb = oy + (long)bz * npix;
    float mW = (float)(ww - 1), mH = (float)(hh - 1);
    int p0 = tid, p1 = tid + 256;
    bool has1 = (p1 < 324);
    int ty0 = p0 / 18, tx0 = p0 % 18;
    int ty1 = p1 / 18, tx1 = p1 % 18;
    float4 wv0 = make_float4(0.f, 0.f, 0.f, 0.f), wv1 = wv0;
    int4 iv0 = make_int4(0, 0, 0, 0), iv1 = iv0;
    {
        int y = i0 - 1 + ty0, x = j0 - 1 + tx0;
        if (p0 < 324 && (unsigned)y < (unsigned)hh && (unsigned)x < (unsigned)ww) {
            float px = (float)x + oxb[y * ww + x];
            float py = (float)y + oyb[y * ww + x];
            px = reflectf(px, mW); py = reflectf(py, mH);
            float x0f = floorf(px), y0f = floorf(py);
            float fx = px - x0f, fy = py - y0f;
            int x0 = min(max((int)x0f, 0), ww - 1);
            int y0 = min(max((int)y0f, 0), hh - 1);
            int x1 = min(x0 + 1, ww - 1);
            int y1 = min(y0 + 1, hh - 1);
            wv0.x = (1.f - fx) * (1.f - fy); wv0.y = fx * (1.f - fy);
            wv0.z = (1.f - fx) * fy;         wv0.w = fx * fy;
            iv0.x = y0 * ww + x0; iv0.z = y1 * ww + x0; iv0.y = (x1 == x0) ? 1 : 0;
        }
        y = i0 - 1 + ty1; x = j0 - 1 + tx1;
        if (has1 && (unsigned)y < (unsigned)hh && (unsigned)x < (unsigned)ww) {
            float px = (float)x + oxb[y * ww + x];
            float py = (float)y + oyb[y * ww + x];
            px = reflectf(px, mW); py = reflectf(py, mH);
            float x0f = floorf(px), y0f = floorf(py);
            float fx = px - x0f, fy = py - y0f;
            int x0 = min(max((int)x0f, 0), ww - 1);
            int y0 = min(max((int)y0f, 0), hh - 1);
            int x1 = min(x0 + 1, ww - 1);
            int y1 = min(y0 + 1, hh - 1);
            wv1.x = (1.f - fx) * (1.f - fy); wv1.y = fx * (1.f - fy);
            wv1.z = (1.f - fx) * fy;         wv1.w = fx * fy;
            iv1.x = y0 * ww + x0; iv1.z = y1 * ww + x0; iv1.y = (x1 == x0) ? 1 : 0;
        }
    }
    half4 w00h0 = h4splat(wv0.x), w01h0 = h4splat(wv0.y), w10h0 = h4splat(wv0.z), w11h0 = h4splat(wv0.w);
    half4 w00h1 = h4splat(wv1.x), w01h1 = h4splat(wv1.y), w10h1 = h4splat(wv1.z), w11h1 = h4splat(wv1.w);
    half4 a00h, a01h, a10h, a11h, b00h, b01h, b10h, b11h;
    #define ISSUE(g) { const half4* pg = tagv + ((long)bz * 64 + (g)) * npix; \
        half8 hA = *(const half8*)(pg + iv0.x); \
        half8 hB = *(const half8*)(pg + iv0.z); \
        a00h = __builtin_shufflevector(hA, hA, 0, 1, 2, 3); \
        a01h = iv0.y ? a00h : __builtin_shufflevector(hA, hA, 4, 5, 6, 7); \
        a10h = __builtin_shufflevector(hB, hB, 0, 1, 2, 3); \
        a11h = iv0.y ? a10h : __builtin_shufflevector(hB, hB, 4, 5, 6, 7); \
        if (has1) { \
            half8 hC = *(const half8*)(pg + iv1.x); \
            half8 hD = *(const half8*)(pg + iv1.z); \
            b00h = __builtin_shufflevector(hC, hC, 0, 1, 2, 3); \
            b01h = iv1.y ? b00h : __builtin_shufflevector(hC, hC, 4, 5, 6, 7); \
            b10h = __builtin_shufflevector(hD, hD, 0, 1, 2, 3); \
            b11h = iv1.y ? b10h : __builtin_shufflevector(hD, hD, 4, 5, 6, 7); } }
    #define WRITEBUF(nb) { \
        sbuf[nb][ty0][tx0] = a00h * w00h0 + a01h * w01h0 + a10h * w10h0 + a11h * w11h0; \
        if (has1) sbuf[nb][ty1][tx1] = b00h * w00h1 + b01h * w01h1 + b10h * w10h1 + b11h * w11h1; }
    ISSUE(g0);
    WRITEBUF(0);
    __syncthreads();
    int ti = tid >> 4, tj = tid & 15;
    int oi = i0 + ti, oj = j0 + tj;
    long outbase = ((long)bz * 64 + g0) * npix + (long)oi * ww + oj;
    #pragma unroll
    for (int gg = 0; gg < GPB; gg++) {
        const int cur = gg & 1;
        if (gg + 1 < GPB) {
            ISSUE(g0 + gg + 1);
            __builtin_amdgcn_sched_barrier(0);
        }
        half4 acch = { (_Float16)0, (_Float16)0, (_Float16)0, (_Float16)0 };
        #pragma unroll
        for (int di = 0; di < 3; di++)
            #pragma unroll
            for (int dj = 0; dj < 3; dj++)
                acch = sbuf[cur][ti + di][tj + dj] * dwWh[gg][di * 3 + dj] + acch;
        float4 accf = to_f4(acch);
        float r0 = fmaxf(accf.x, 0.f), r1 = fmaxf(accf.y, 0.f);
        float r2 = fmaxf(accf.z, 0.f), r3 = fmaxf(accf.w, 0.f);
        float4 o;
        o.x = (r0 * pwW[gg][0]  + r1 * pwW[gg][1]  + r2 * pwW[gg][2]  + r3 * pwW[gg][3])  * wscW[gg][0];
        o.y = (r0 * pwW[gg][4]  + r1 * pwW[gg][5]  + r2 * pwW[gg][6]  + r3 * pwW[gg][7])  * wscW[gg][1];
        o.z = (r0 * pwW[gg][8]  + r1 * pwW[gg][9]  + r2 * pwW[gg][10] + r3 * pwW[gg][11]) * wscW[gg][2];
        o.w = (r0 * pwW[gg][12] + r1 * pwW[gg][13] + r2 * pwW[gg][14] + r3 * pwW[gg][15]) * wscW[gg][3];
        outv[outbase + (long)gg * npix] = to_h4(o);
        if (gg + 1 < GPB) {
            WRITEBUF(cur ^ 1);
            __syncthreads();
        }
    }
    #undef ISSUE
    #undef WRITEBUF
}

// ---------------- k_snake_final: GPB=8, deferred stores + pinned prefetch ----------------
__global__ __launch_bounds__(256, 4) void k_snake_final(
    const half4* __restrict__ tagv,
    const half4* __restrict__ tagp1v,
    const float* __restrict__ ox, const float* __restrict__ oy,
    const float* __restrict__ dww, const float* __restrict__ pww,
    const float* __restrict__ wsc,
    const float* __restrict__ x,
    const float* __restrict__ bw, const float* __restrict__ bb,
    const float* __restrict__ bs,
    float* __restrict__ out) {
    const int GPB = 8, hh = 64, ww = 64, npix = 4096;
    __shared__ half4 sbuf[2][18][19];
    __shared__ float xs[2][34][36];
    __shared__ half4 dwWh[GPB][9];
    __shared__ float pwW[GPB][16];
    __shared__ float wscW[GPB][4];
    __shared__ float bwW[GPB][9];
    __shared__ float bbW[GPB];
    __shared__ float bsW[GPB];
    int tile = blockIdx.x;
    int g0 = blockIdx.y * GPB;
    int bz = blockIdx.z;
    int i0 = (tile >> 2) * 16;
    int j0 = (tile & 3) * 16;
    int yy0 = 2 * i0, xx0 = 2 * j0;
    int tid = threadIdx.x;
    for (int t = tid; t < GPB * 36; t += 256) {
        int gg = t / 36, rem = t % 36, cc = rem / 9, tap = rem % 9;
        ((_Float16*)&dwWh[gg][tap])[cc] = (_Float16)dww[g0 * 36 + t];
    }
    for (int t = tid; t < GPB * 16; t += 256) pwW[t / 16][t % 16] = pww[g0 * 16 + t];
    for (int t = tid; t < GPB * 4;  t += 256) wscW[t / 4][t % 4]  = wsc[g0 * 4 + t];
    for (int t = tid; t < GPB * 9;  t += 256) bwW[t / 9][t % 9]   = bw[g0 * 9 + t];
    if (tid < GPB) { bbW[tid] = bb[g0 + tid]; bsW[tid] = bs[g0 + tid]; }
    const float* oxb = ox + (long)bz * npix;
    const float* oyb = oy + (long)bz * npix;
    float mW = 63.f, mH = 63.f;
    int p0 = tid, p1 = tid + 256;
    bool has1 = (p1 < 324);
    int ty0 = p0 / 18, tx0 = p0 % 18;
    int ty1 = p1 / 18, tx1 = p1 % 18;
    float4 wv0 = make_float4(0.f, 0.f, 0.f, 0.f), wv1 = wv0;
    int4 iv0 = make_int4(0, 0, 0, 0), iv1 = iv0;
    {
        int y = i0 - 1 + ty0, xg = j0 - 1 + tx0;
        if ((unsigned)y < (unsigned)hh && (unsigned)xg < (unsigned)ww) {
            float px = (float)xg + oxb[y * ww + xg];
            float py = (float)y + oyb[y * ww + xg];
            px = reflectf(px, mW); py = reflectf(py, mH);
            float x0f = floorf(px), y0f = floorf(py);
            float fx = px - x0f, fy = py - y0f;
            int x0 = min(max((int)x0f, 0), ww - 1);
            int y0 = min(max((int)y0f, 0), hh - 1);
            int x1 = min(x0 + 1, ww - 1);
            int y1 = min(y0 + 1, hh - 1);
            wv0.x = (1.f - fx) * (1.f - fy); wv0.y = fx * (1.f - fy);
            wv0.z = (1.f - fx) * fy;         wv0.w = fx * fy;
            iv0.x = y0 * ww + x0; iv0.z = y1 * ww + x0; iv0.y = (x1 == x0) ? 1 : 0;
        }
        y = i0 - 1 + ty1; xg = j0 - 1 + tx1;
        if (has1 && (unsigned)y < (unsigned)hh && (unsigned)xg < (unsigned)ww) {
            float px = (float)xg + oxb[y * ww + xg];
            float py = (float)y + oyb[y * ww + xg];
            px = reflectf(px, mW); py = reflectf(py, mH);
            float x0f = floorf(px), y0f = floorf(py);
            float fx = px - x0f, fy = py - y0f;
            int x0 = min(max((int)x0f, 0), ww - 1);
            int y0 = min(max((int)y0f, 0), hh - 1);
            int x1 = min(x0 + 1, ww - 1);
            int y1 = min(y0 + 1, hh - 1);
            wv1.x = (1.f - fx) * (1.f - fy); wv1.y = fx * (1.f - fy);
            wv1.z = (1.f - fx) * fy;         wv1.w = fx * fy;
            iv1.x = y0 * ww + x0; iv1.z = y1 * ww + x0; iv1.y = (x1 == x0) ? 1 : 0;
        }
    }
    half4 w00h0 = h4splat(wv0.x), w01h0 = h4splat(wv0.y), w10h0 = h4splat(wv0.z), w11h0 = h4splat(wv0.w);
    half4 w00h1 = h4splat(wv1.x), w01h1 = h4splat(wv1.y), w10h1 = h4splat(wv1.z), w11h1 = h4splat(wv1.w);
    half4 a00h, a01h, a10h, a11h, b00h, b01h, b10h, b11h;
    float xr[5];
    #define ISSUE(g) { const half4* pg = tagv + ((long)bz * 64 + (g)) * npix; \
        half8 hA = *(const half8*)(pg + iv0.x); \
        half8 hB = *(const half8*)(pg + iv0.z); \
        a00h = __builtin_shufflevector(hA, hA, 0, 1, 2, 3); \
        a01h = iv0.y ? a00h : __builtin_shufflevector(hA, hA, 4, 5, 6, 7); \
        a10h = __builtin_shufflevector(hB, hB, 0, 1, 2, 3); \
        a11h = iv0.y ? a10h : __builtin_shufflevector(hB, hB, 4, 5, 6, 7); \
        if (has1) { \
            half8 hC = *(const half8*)(pg + iv1.x); \
            half8 hD = *(const half8*)(pg + iv1.z); \
            b00h = __builtin_shufflevector(hC, hC, 0, 1, 2, 3); \
            b01h = iv1.y ? b00h : __builtin_shufflevector(hC, hC, 4, 5, 6, 7); \
            b10h = __builtin_shufflevector(hD, hD, 0, 1, 2, 3); \
            b11h = iv1.y ? b10h : __builtin_shufflevector(hD, hD, 4, 5, 6, 7); } }
    #define WRITEBUF(nb) { \
        sbuf[nb][ty0][tx0] = a00h * w00h0 + a01h * w01h0 + a10h * w10h0 + a11h * w11h0; \
        if (has1) sbuf[nb][ty1][tx1] = b00h * w00h1 + b01h * w01h1 + b10h * w10h1 + b11h * w11h1; }
    #define XLOAD(c) { const float* xbc = x + (long)(bz * 64 + (c)) * 16384; \
        _Pragma("unroll") \
        for (int q = 0; q < 5; q++) { int p = tid + q * 256; float v = 0.f; \
            if (p < 1156) { int r = p / 34, qq = p % 34; \
                int y = yy0 - 1 + r, xg = xx0 - 1 + qq; \
                if ((unsigned)y < 128u && (unsigned)xg < 128u) v = xbc[y * 128 + xg]; } \
            xr[q] = v; } }
    #define XWRITE(nb) { _Pragma("unroll") \
        for (int q = 0; q < 5; q++) { int p = tid + q * 256; \
            if (p < 1156) xs[nb][p / 34][p % 34] = xr[q]; } }
    int ti = tid >> 4, tj = tid & 15;
    int i = i0 + ti, j = j0 + tj;
    long t1base = ((long)(bz * 64)) * 1024 + (long)(i >> 1) * 32 + (j >> 1);
    ISSUE(g0);
    XLOAD(g0);
    half4 dcur_h = tagp1v[t1base + (long)g0 * 1024];
    WRITEBUF(0);
    XWRITE(0);
    __syncthreads();
    int yy = 2 * i, xx = 2 * j;
    float sr = (i & 1) ? -1.f : 1.f;
    float sc = (j & 1) ? -1.f : 1.f;
    int a = 2 * ti, bq = 2 * tj;
    float4 oreg[GPB];
    #pragma unroll
    for (int gg = 0; gg < GPB; gg++) {
        const int cur = gg & 1;
        half4 dnx_h;
        if (gg + 1 < GPB) {
            ISSUE(g0 + gg + 1);
            XLOAD(g0 + gg + 1);
            dnx_h = tagp1v[t1base + (long)(g0 + gg + 1) * 1024];
            __builtin_amdgcn_sched_barrier(0);   // pin prefetch issue above the conv
        }
        float4 d = to_f4(dcur_h);
        half4 acch = { (_Float16)0, (_Float16)0, (_Float16)0, (_Float16)0 };
        #pragma unroll
        for (int di = 0; di < 3; di++)
            #pragma unroll
            for (int dj = 0; dj < 3; dj++)
                acch = sbuf[cur][ti + di][tj + dj] * dwWh[gg][di * 3 + dj] + acch;
        float4 accf = to_f4(acch);
        float r0 = fmaxf(accf.x, 0.f), r1 = fmaxf(accf.y, 0.f);
        float r2 = fmaxf(accf.z, 0.f), r3 = fmaxf(accf.w, 0.f);
        float4 o;
        o.x = (r0 * pwW[gg][0]  + r1 * pwW[gg][1]  + r2 * pwW[gg][2]  + r3 * pwW[gg][3])  * wscW[gg][0];
        o.y = (r0 * pwW[gg][4]  + r1 * pwW[gg][5]  + r2 * pwW[gg][6]  + r3 * pwW[gg][7])  * wscW[gg][1];
        o.z = (r0 * pwW[gg][8]  + r1 * pwW[gg][9]  + r2 * pwW[gg][10] + r3 * pwW[gg][11]) * wscW[gg][2];
        o.w = (r0 * pwW[gg][12] + r1 * pwW[gg][13] + r2 * pwW[gg][14] + r3 * pwW[gg][15]) * wscW[gg][3];
        float nv = 0.5f * (d.x + sr * d.y + sc * d.z + sr * sc * d.w);
        float c0 = o.x + nv;
        float c1 = o.y, c2 = o.z, c3 = o.w;
        float rec00 = 0.5f * (c0 + c1 + c2 + c3);
        float rec01 = 0.5f * (c0 + c1 - c2 - c3);
        float rec10 = 0.5f * (c0 - c1 + c2 - c3);
        float rec11 = 0.5f * (c0 - c1 - c2 + c3);
        float bias = bbW[gg], scale = bsW[gg];
        float w0 = bwW[gg][0], w1 = bwW[gg][1], w2 = bwW[gg][2];
        float w3 = bwW[gg][3], w4 = bwW[gg][4], w5 = bwW[gg][5];
        float w6 = bwW[gg][6], w7 = bwW[gg][7], w8 = bwW[gg][8];
        float xv[4][4];
        #pragma unroll
        for (int r = 0; r < 4; r++) {
            float2 lo = *(const float2*)&xs[cur][a + r][bq];
            float2 hi = *(const float2*)&xs[cur][a + r][bq + 2];
            xv[r][0] = lo.x; xv[r][1] = lo.y; xv[r][2] = hi.x; xv[r][3] = hi.y;
        }
        #define CONV(dy,dx) ({ \
            float accc = bias; \
            accc = fmaf(xv[dy+0][dx+0], w0, accc); \
            accc = fmaf(xv[dy+0][dx+1], w1, accc); \
            accc = fmaf(xv[dy+0][dx+2], w2, accc); \
            accc = fmaf(xv[dy+1][dx+0], w3, accc); \
            accc = fmaf(xv[dy+1][dx+1], w4, accc); \
            accc = fmaf(xv[dy+1][dx+2], w5, accc); \
            accc = fmaf(xv[dy+2][dx+0], w6, accc); \
            accc = fmaf(xv[dy+2][dx+1], w7, accc); \
            accc = fmaf(xv[dy+2][dx+2], w8, accc); \
            accc; })
        oreg[gg].x = scale * CONV(0,0) + rec00;
        oreg[gg].y = scale * CONV(0,1) + rec01;
        oreg[gg].z = scale * CONV(1,0) + rec10;
        oreg[gg].w = scale * CONV(1,1) + rec11;
        #undef CONV
        if (gg + 1 < GPB) {
            dcur_h = dnx_h;
            WRITEBUF(cur ^ 1);
            XWRITE(cur ^ 1);
            __syncthreads();
        }
    }
    // deferred output stores (no store-drain inside the loop's barriers)
    #pragma unroll
    for (int gg = 0; gg < GPB; gg++) {
        float* ob = out + (((long)(bz * 64 + g0 + gg) * 128) + yy) * 128 + xx;
        *(float2*)ob         = make_float2(oreg[gg].x, oreg[gg].y);
        *(float2*)(ob + 128) = make_float2(oreg[gg].z, oreg[gg].w);
    }
    #undef ISSUE
    #undef WRITEBUF
    #undef XLOAD
    #undef XWRITE
}

// ---------------- launch ----------------
extern "C" void kernel_launch(void* const* d_in, const int* in_sizes, int n_in,
                              void* d_out, int out_size, void* d_ws, size_t ws_size,
                              hipStream_t stream) {
    const float* x     = (const float*)d_in[0];
    const float* bw    = (const float*)d_in[1];
    const float* bb    = (const float*)d_in[2];
    const float* bs    = (const float*)d_in[3];
    const float* offw0 = (const float*)d_in[4];
    const float* offb0 = (const float*)d_in[5];
    const float* dww0  = (const float*)d_in[6];
    const float* pww0  = (const float*)d_in[7];
    const float* wsc0  = (const float*)d_in[8];
    const float* offw1 = (const float*)d_in[9];
    const float* offb1 = (const float*)d_in[10];
    const float* dww1  = (const float*)d_in[11];
    const float* pww1  = (const float*)d_in[12];
    const float* wsc1  = (const float*)d_in[13];
    float* out = (float*)d_out;
    float* ws = (float*)d_ws;

    // workspace layout (float offsets)
    half4*     tag0h  = (half4*)(ws + 0L);
    half4*     tag1h  = (half4*)(ws + 8388608L);
    half4*     tagp1h = (half4*)(ws + 10485760L);
    _Float16*  part0h = (_Float16*)(ws + 12582912L);
    _Float16*  part1h = (_Float16*)(ws + 13631488L);
    float* avgw = ws + 13893632L;
    float* avgb = ws + 13902848L;
    float* ox0  = ws + 13902852L;
    float* oy0  = ws + 13968388L;
    float* ox1  = ws + 14033924L;
    float* oy1  = ws + 14050308L;

    k_wt01<<<4096, 256, 0, stream>>>(x, tag0h, tag1h, offw0, offb0, offw1, offb1, avgw, avgb);
    k_off_part_both<<<dim3(20, 16, 16), 256, 0, stream>>>(tag0h, tag1h, avgw, part0h, part1h);
    k_off_red_both<<<320, 256, 0, stream>>>(part0h, part1h, avgb, ox0, oy0, ox1, oy1);
    k_snake<4><<<dim3(4, 16, 16), 256, 0, stream>>>(tag1h, ox1, oy1, dww1, pww1, wsc1,
                                                    tagp1h, 16, 32, 32);
    k_snake_final<<<dim3(16, 8, 16), 256, 0, stream>>>(
        tag0h, tagp1h, ox0, oy0, dww0, pww0, wsc0,
        x, bw, bb, bs, out);
}

// Round 18
// 115.856 us; speedup vs baseline: 6.1509x; 6.1509x over previous
//
#include <hip/hip_runtime.h>

typedef _Float16 half4 __attribute__((ext_vector_type(4)));
typedef _Float16 half8 __attribute__((ext_vector_type(8), aligned(8)));
typedef _Float16 half8a __attribute__((ext_vector_type(8), aligned(16)));

static __device__ __forceinline__ half4 to_h4(float4 v) {
    half4 h; h.x = (_Float16)v.x; h.y = (_Float16)v.y; h.z = (_Float16)v.z; h.w = (_Float16)v.w; return h;
}
static __device__ __forceinline__ float4 to_f4(half4 h) {
    return make_float4((float)h.x, (float)h.y, (float)h.z, (float)h.w);
}
static __device__ __forceinline__ half4 h4splat(float v) {
    _Float16 h = (_Float16)v; half4 r = { h, h, h, h }; return r;
}

// ---------------- helpers ----------------
static __device__ __forceinline__ float reflectf(float coord, float m) {
    float period = 2.0f * m;
    float c = fmodf(fabsf(coord), period);
    c = (c > m) ? (period - c) : c;
    return fminf(fmaxf(c, 0.0f), m);
}

// ---------------- k_wt01: fused Haar DWT levels 0+1, with k_prep folded in ----------------
__global__ __launch_bounds__(256) void k_wt01(
    const float* __restrict__ x, half4* __restrict__ tag0v, half4* __restrict__ tag1v,
    const float* __restrict__ offw0, const float* __restrict__ offb0,
    const float* __restrict__ offw1, const float* __restrict__ offb1,
    float* __restrict__ avgw, float* __restrict__ avgb) {
    int id = blockIdx.x * 256 + threadIdx.x;
    if (id < 2 * 2 * 2304) {
        int l = id / 4608;
        int rem = id % 4608;
        int d = rem / 2304;
        int r = rem % 2304;
        const float* w = l ? offw1 : offw0;
        float s = w[(d * 3 + 0) * 2304 + r] + w[(d * 3 + 1) * 2304 + r] + w[(d * 3 + 2) * 2304 + r];
        avgw[id] = s * (1.0f / 3.0f);
        if (id == 0) {
            avgb[0] = (offb0[0] + offb0[1] + offb0[2]) * (1.0f / 3.0f);
            avgb[1] = (offb0[3] + offb0[4] + offb0[5]) * (1.0f / 3.0f);
            avgb[2] = (offb1[0] + offb1[1] + offb1[2]) * (1.0f / 3.0f);
            avgb[3] = (offb1[3] + offb1[4] + offb1[5]) * (1.0f / 3.0f);
        }
    }
    if (id >= 16 * 64 * 32 * 32) return;
    int j1 = id & 31; int t = id >> 5;
    int i1 = t & 31; t >>= 5;
    int c = t & 63; int b = t >> 6;
    const float* p = x + ((long)(b * 64 + c) * 128 + 4 * i1) * 128 + 4 * j1;
    float4 r0 = *(const float4*)p;
    float4 r1 = *(const float4*)(p + 128);
    float4 r2 = *(const float4*)(p + 256);
    float4 r3 = *(const float4*)(p + 384);
    #define HAAR(a0,a1,a2,a3) make_float4(0.5f*((a0)+(a1)+(a2)+(a3)), 0.5f*((a0)+(a1)-(a2)-(a3)), \
                                          0.5f*((a0)-(a1)+(a2)-(a3)), 0.5f*((a0)-(a1)-(a2)+(a3)))
    float4 t00 = HAAR(r0.x, r0.y, r1.x, r1.y);
    float4 t01 = HAAR(r0.z, r0.w, r1.z, r1.w);
    float4 t10 = HAAR(r2.x, r2.y, r3.x, r3.y);
    float4 t11 = HAAR(r2.z, r2.w, r3.z, r3.w);
    long pbase = (long)(b * 64 + c) * 4096;
    int i0 = 2 * i1, j0 = 2 * j1;
    half4 h00 = to_h4(t00), h01 = to_h4(t01), h10 = to_h4(t10), h11 = to_h4(t11);
    half8a row0 = { h00.x, h00.y, h00.z, h00.w, h01.x, h01.y, h01.z, h01.w };
    half8a row1 = { h10.x, h10.y, h10.z, h10.w, h11.x, h11.y, h11.z, h11.w };
    *(half8a*)&tag0v[pbase + (long)i0 * 64 + j0]       = row0;
    *(half8a*)&tag0v[pbase + (long)(i0 + 1) * 64 + j0] = row1;
    tag1v[(long)(b * 64 + c) * 1024 + (long)i1 * 32 + j1] = to_h4(HAAR(t00.x, t01.x, t10.x, t11.x));
    #undef HAAR
}

// ---------------- k_off_part_both: LDS-staged tile conv, both levels ----------------
__global__ __launch_bounds__(256) void k_off_part_both(
    const half4* __restrict__ tag0, const half4* __restrict__ tag1,
    const float* __restrict__ avgw,
    _Float16* __restrict__ part0, _Float16* __restrict__ part1) {
    int bx = blockIdx.x;
    const half4* tagv; _Float16* part; int level, hh, ww, tilesX;
    if (bx < 16) { tagv = tag0; part = part0; level = 0; hh = 64; ww = 64; tilesX = 4; }
    else { bx -= 16; tagv = tag1; part = part1; level = 1; hh = 32; ww = 32; tilesX = 2; }
    int chunk = blockIdx.y;
    int b = blockIdx.z;
    int npix = hh * ww;
    int totpix = 16 * npix;
    int i0 = (bx / tilesX) * 16, j0 = (bx % tilesX) * 16;
    __shared__ half4 s[4][18][19];
    __shared__ float wls[2][4][9][4];
    int tid = threadIdx.x;
    const float* wsrc = avgw + level * 4608;
    for (int t = tid; t < 288; t += 256) {
        int d = t / 144, rem = t % 144;
        int gg = rem / 36; int tap = (rem % 36) / 4; int cc = rem & 3;
        wls[d][gg][tap][cc] = wsrc[d * 2304 + (chunk * 16 + gg * 4 + cc) * 9 + tap];
    }
    const half4 zh = { (_Float16)0, (_Float16)0, (_Float16)0, (_Float16)0 };
    for (int p = tid; p < 324; p += 256) {
        int ty = p / 18, tx = p % 18;
        int y = i0 - 1 + ty, xg = j0 - 1 + tx;
        bool ok = (unsigned)y < (unsigned)hh && (unsigned)xg < (unsigned)ww;
        #pragma unroll
        for (int gg = 0; gg < 4; gg++) {
            const half4* pg = tagv + ((long)b * 64 + chunk * 4 + gg) * npix;
            s[gg][ty][tx] = ok ? pg[y * ww + xg] : zh;
        }
    }
    __syncthreads();
    int ti = tid >> 4, tj = tid & 15;
    float ax = 0.f, ay = 0.f;
    #pragma unroll
    for (int gg = 0; gg < 4; gg++) {
        #pragma unroll
        for (int di = 0; di < 3; di++) {
            #pragma unroll
            for (int dj = 0; dj < 3; dj++) {
                float4 v = to_f4(s[gg][ti + di][tj + dj]);
                const float* wx = &wls[0][gg][di * 3 + dj][0];
                const float* wy = &wls[1][gg][di * 3 + dj][0];
                ax = fmaf(v.x, wx[0], ax); ax = fmaf(v.y, wx[1], ax);
                ax = fmaf(v.z, wx[2], ax); ax = fmaf(v.w, wx[3], ax);
                ay = fmaf(v.x, wy[0], ay); ay = fmaf(v.y, wy[1], ay);
                ay = fmaf(v.z, wy[2], ay); ay = fmaf(v.w, wy[3], ay);
            }
        }
    }
    long pid = (long)b * npix + (long)(i0 + ti) * ww + (j0 + tj);
    part[(long)chunk * totpix + pid]        = (_Float16)ax;
    part[((long)16 + chunk) * totpix + pid] = (_Float16)ay;
}

// ---------------- k_off_red_both ----------------
__global__ __launch_bounds__(256) void k_off_red_both(
    const _Float16* __restrict__ part0, const _Float16* __restrict__ part1,
    const float* __restrict__ avgb,
    float* __restrict__ ox0, float* __restrict__ oy0,
    float* __restrict__ ox1, float* __restrict__ oy1) {
    int bx = blockIdx.x;
    const _Float16* part; float* ox; float* oy; int level, totpix;
    if (bx < 256) { part = part0; ox = ox0; oy = oy0; level = 0; totpix = 65536; }
    else          { bx -= 256; part = part1; ox = ox1; oy = oy1; level = 1; totpix = 16384; }
    int id = bx * 256 + threadIdx.x;
    if (id >= totpix) return;
    float sx = avgb[level * 2 + 0], sy = avgb[level * 2 + 1];
    #pragma unroll
    for (int c = 0; c < 16; c++) sx += (float)part[(long)c * totpix + id];
    #pragma unroll
    for (int c = 0; c < 16; c++) sy += (float)part[((long)16 + c) * totpix + id];
    ox[id] = sx; oy[id] = sy;
}

// ---------------- k_snake (level 1): packed-fp16 sbuf/bilinear/conv (gather) ----------------
template<int GPB>
__global__ __launch_bounds__(256, 4) void k_snake(
    const half4* __restrict__ tagv,
    const float* __restrict__ ox, const float* __restrict__ oy,
    const float* __restrict__ dww, const float* __restrict__ pww,
    const float* __restrict__ wsc,
    half4* __restrict__ outv, int B, int hh, int ww) {
    __shared__ half4 sbuf[2][18][19];
    __shared__ half4 dwWh[GPB][9];
    __shared__ float pwW[GPB][16];
    __shared__ float wscW[GPB][4];
    int tilesX = ww >> 4;
    int tile = blockIdx.x;
    int g0 = blockIdx.y * GPB;
    int bz = blockIdx.z;
    int i0 = (tile / tilesX) * 16;
    int j0 = (tile % tilesX) * 16;
    int tid = threadIdx.x;
    for (int t = tid; t < GPB * 36; t += 256) {
        int gg = t / 36, rem = t % 36, cc = rem / 9, tap = rem % 9;
        ((_Float16*)&dwWh[gg][tap])[cc] = (_Float16)dww[g0 * 36 + t];
    }
    for (int t = tid; t < GPB * 16; t += 256) pwW[t / 16][t % 16] = pww[g0 * 16 + t];
    for (int t = tid; t < GPB * 4;  t += 256) wscW[t / 4][t % 4]  = wsc[g0 * 4 + t];
    int npix = hh * ww;
    const float* oxb = ox + (long)bz * npix;
    const float* oyb = oy + (long)bz * npix;
    float mW = (float)(ww - 1), mH = (float)(hh - 1);
    int p0 = tid, p1 = tid + 256;
    bool has1 = (p1 < 324);
    int ty0 = p0 / 18, tx0 = p0 % 18;
    int ty1 = p1 / 18, tx1 = p1 % 18;
    float4 wv0 = make_float4(0.f, 0.f, 0.f, 0.f), wv1 = wv0;
    int4 iv0 = make_int4(0, 0, 0, 0), iv1 = iv0;
    {
        int y = i0 - 1 + ty0, x = j0 - 1 + tx0;
        if (p0 < 324 && (unsigned)y < (unsigned)hh && (unsigned)x < (unsigned)ww) {
            float px = (float)x + oxb[y * ww + x];
            float py = (float)y + oyb[y * ww + x];
            px = reflectf(px, mW); py = reflectf(py, mH);
            float x0f = floorf(px), y0f = floorf(py);
            float fx = px - x0f, fy = py - y0f;
            int x0 = min(max((int)x0f, 0), ww - 1);
            int y0 = min(max((int)y0f, 0), hh - 1);
            int x1 = min(x0 + 1, ww - 1);
            int y1 = min(y0 + 1, hh - 1);
            wv0.x = (1.f - fx) * (1.f - fy); wv0.y = fx * (1.f - fy);
            wv0.z = (1.f - fx) * fy;         wv0.w = fx * fy;
            iv0.x = y0 * ww + x0; iv0.z = y1 * ww + x0; iv0.y = (x1 == x0) ? 1 : 0;
        }
        y = i0 - 1 + ty1; x = j0 - 1 + tx1;
        if (has1 && (unsigned)y < (unsigned)hh && (unsigned)x < (unsigned)ww) {
            float px = (float)x + oxb[y * ww + x];
            float py = (float)y + oyb[y * ww + x];
            px = reflectf(px, mW); py = reflectf(py, mH);
            float x0f = floorf(px), y0f = floorf(py);
            float fx = px - x0f, fy = py - y0f;
            int x0 = min(max((int)x0f, 0), ww - 1);
            int y0 = min(max((int)y0f, 0), hh - 1);
            int x1 = min(x0 + 1, ww - 1);
            int y1 = min(y0 + 1, hh - 1);
            wv1.x = (1.f - fx) * (1.f - fy); wv1.y = fx * (1.f - fy);
            wv1.z = (1.f - fx) * fy;         wv1.w = fx * fy;
            iv1.x = y0 * ww + x0; iv1.z = y1 * ww + x0; iv1.y = (x1 == x0) ? 1 : 0;
        }
    }
    half4 w00h0 = h4splat(wv0.x), w01h0 = h4splat(wv0.y), w10h0 = h4splat(wv0.z), w11h0 = h4splat(wv0.w);
    half4 w00h1 = h4splat(wv1.x), w01h1 = h4splat(wv1.y), w10h1 = h4splat(wv1.z), w11h1 = h4splat(wv1.w);
    half4 a00h, a01h, a10h, a11h, b00h, b01h, b10h, b11h;
    #define ISSUE(g) { const half4* pg = tagv + ((long)bz * 64 + (g)) * npix; \
        half8 hA = *(const half8*)(pg + iv0.x); \
        half8 hB = *(const half8*)(pg + iv0.z); \
        a00h = __builtin_shufflevector(hA, hA, 0, 1, 2, 3); \
        a01h = iv0.y ? a00h : __builtin_shufflevector(hA, hA, 4, 5, 6, 7); \
        a10h = __builtin_shufflevector(hB, hB, 0, 1, 2, 3); \
        a11h = iv0.y ? a10h : __builtin_shufflevector(hB, hB, 4, 5, 6, 7); \
        if (has1) { \
            half8 hC = *(const half8*)(pg + iv1.x); \
            half8 hD = *(const half8*)(pg + iv1.z); \
            b00h = __builtin_shufflevector(hC, hC, 0, 1, 2, 3); \
            b01h = iv1.y ? b00h : __builtin_shufflevector(hC, hC, 4, 5, 6, 7); \
            b10h = __builtin_shufflevector(hD, hD, 0, 1, 2, 3); \
            b11h = iv1.y ? b10h : __builtin_shufflevector(hD, hD, 4, 5, 6, 7); } }
    #define WRITEBUF(nb) { \
        sbuf[nb][ty0][tx0] = a00h * w00h0 + a01h * w01h0 + a10h * w10h0 + a11h * w11h0; \
        if (has1) sbuf[nb][ty1][tx1] = b00h * w00h1 + b01h * w01h1 + b10h * w10h1 + b11h * w11h1; }
    ISSUE(g0);
    WRITEBUF(0);
    __syncthreads();
    int ti = tid >> 4, tj = tid & 15;
    int oi = i0 + ti, oj = j0 + tj;
    long outbase = ((long)bz * 64 + g0) * npix + (long)oi * ww + oj;
    #pragma unroll
    for (int gg = 0; gg < GPB; gg++) {
        const int cur = gg & 1;
        if (gg + 1 < GPB) ISSUE(g0 + gg + 1);
        half4 acch = { (_Float16)0, (_Float16)0, (_Float16)0, (_Float16)0 };
        #pragma unroll
        for (int di = 0; di < 3; di++)
            #pragma unroll
            for (int dj = 0; dj < 3; dj++)
                acch = sbuf[cur][ti + di][tj + dj] * dwWh[gg][di * 3 + dj] + acch;
        float4 accf = to_f4(acch);
        float r0 = fmaxf(accf.x, 0.f), r1 = fmaxf(accf.y, 0.f);
        float r2 = fmaxf(accf.z, 0.f), r3 = fmaxf(accf.w, 0.f);
        float4 o;
        o.x = (r0 * pwW[gg][0]  + r1 * pwW[gg][1]  + r2 * pwW[gg][2]  + r3 * pwW[gg][3])  * wscW[gg][0];
        o.y = (r0 * pwW[gg][4]  + r1 * pwW[gg][5]  + r2 * pwW[gg][6]  + r3 * pwW[gg][7])  * wscW[gg][1];
        o.z = (r0 * pwW[gg][8]  + r1 * pwW[gg][9]  + r2 * pwW[gg][10] + r3 * pwW[gg][11]) * wscW[gg][2];
        o.w = (r0 * pwW[gg][12] + r1 * pwW[gg][13] + r2 * pwW[gg][14] + r3 * pwW[gg][15]) * wscW[gg][3];
        outv[outbase + (long)gg * npix] = to_h4(o);
        if (gg + 1 < GPB) {
            WRITEBUF(cur ^ 1);
            __syncthreads();
        }
    }
    #undef ISSUE
    #undef WRITEBUF
}

// ---------------- k_snake_final: packed-fp16 snake + inverse DWTs + base conv (GPB=8, d-prefetch) ----------------
__global__ __launch_bounds__(256, 4) void k_snake_final(
    const half4* __restrict__ tagv,
    const half4* __restrict__ tagp1v,
    const float* __restrict__ ox, const float* __restrict__ oy,
    const float* __restrict__ dww, const float* __restrict__ pww,
    const float* __restrict__ wsc,
    const float* __restrict__ x,
    const float* __restrict__ bw, const float* __restrict__ bb,
    const float* __restrict__ bs,
    float* __restrict__ out) {
    const int GPB = 8, hh = 64, ww = 64, npix = 4096;
    __shared__ half4 sbuf[2][18][19];
    __shared__ float xs[2][34][36];
    __shared__ half4 dwWh[GPB][9];
    __shared__ float pwW[GPB][16];
    __shared__ float wscW[GPB][4];
    __shared__ float bwW[GPB][9];
    __shared__ float bbW[GPB];
    __shared__ float bsW[GPB];
    int tile = blockIdx.x;
    int g0 = blockIdx.y * GPB;
    int bz = blockIdx.z;
    int i0 = (tile >> 2) * 16;
    int j0 = (tile & 3) * 16;
    int yy0 = 2 * i0, xx0 = 2 * j0;
    int tid = threadIdx.x;
    for (int t = tid; t < GPB * 36; t += 256) {
        int gg = t / 36, rem = t % 36, cc = rem / 9, tap = rem % 9;
        ((_Float16*)&dwWh[gg][tap])[cc] = (_Float16)dww[g0 * 36 + t];
    }
    for (int t = tid; t < GPB * 16; t += 256) pwW[t / 16][t % 16] = pww[g0 * 16 + t];
    for (int t = tid; t < GPB * 4;  t += 256) wscW[t / 4][t % 4]  = wsc[g0 * 4 + t];
    for (int t = tid; t < GPB * 9;  t += 256) bwW[t / 9][t % 9]   = bw[g0 * 9 + t];
    if (tid < GPB) { bbW[tid] = bb[g0 + tid]; bsW[tid] = bs[g0 + tid]; }
    const float* oxb = ox + (long)bz * npix;
    const float* oyb = oy + (long)bz * npix;
    float mW = 63.f, mH = 63.f;
    int p0 = tid, p1 = tid + 256;
    bool has1 = (p1 < 324);
    int ty0 = p0 / 18, tx0 = p0 % 18;
    int ty1 = p1 / 18, tx1 = p1 % 18;
    float4 wv0 = make_float4(0.f, 0.f, 0.f, 0.f), wv1 = wv0;
    int4 iv0 = make_int4(0, 0, 0, 0), iv1 = iv0;
    {
        int y = i0 - 1 + ty0, xg = j0 - 1 + tx0;
        if ((unsigned)y < (unsigned)hh && (unsigned)xg < (unsigned)ww) {
            float px = (float)xg + oxb[y * ww + xg];
            float py = (float)y + oyb[y * ww + xg];
            px = reflectf(px, mW); py = reflectf(py, mH);
            float x0f = floorf(px), y0f = floorf(py);
            float fx = px - x0f, fy = py - y0f;
            int x0 = min(max((int)x0f, 0), ww - 1);
            int y0 = min(max((int)y0f, 0), hh - 1);
            int x1 = min(x0 + 1, ww - 1);
            int y1 = min(y0 + 1, hh - 1);
            wv0.x = (1.f - fx) * (1.f - fy); wv0.y = fx * (1.f - fy);
            wv0.z = (1.f - fx) * fy;         wv0.w = fx * fy;
            iv0.x = y0 * ww + x0; iv0.z = y1 * ww + x0; iv0.y = (x1 == x0) ? 1 : 0;
        }
        y = i0 - 1 + ty1; xg = j0 - 1 + tx1;
        if (has1 && (unsigned)y < (unsigned)hh && (unsigned)xg < (unsigned)ww) {
            float px = (float)xg + oxb[y * ww + xg];
            float py = (float)y + oyb[y * ww + xg];
            px = reflectf(px, mW); py = reflectf(py, mH);
            float x0f = floorf(px), y0f = floorf(py);
            float fx = px - x0f, fy = py - y0f;
            int x0 = min(max((int)x0f, 0), ww - 1);
            int y0 = min(max((int)y0f, 0), hh - 1);
            int x1 = min(x0 + 1, ww - 1);
            int y1 = min(y0 + 1, hh - 1);
            wv1.x = (1.f - fx) * (1.f - fy); wv1.y = fx * (1.f - fy);
            wv1.z = (1.f - fx) * fy;         wv1.w = fx * fy;
            iv1.x = y0 * ww + x0; iv1.z = y1 * ww + x0; iv1.y = (x1 == x0) ? 1 : 0;
        }
    }
    half4 w00h0 = h4splat(wv0.x), w01h0 = h4splat(wv0.y), w10h0 = h4splat(wv0.z), w11h0 = h4splat(wv0.w);
    half4 w00h1 = h4splat(wv1.x), w01h1 = h4splat(wv1.y), w10h1 = h4splat(wv1.z), w11h1 = h4splat(wv1.w);
    half4 a00h, a01h, a10h, a11h, b00h, b01h, b10h, b11h;
    float xr[5];
    #define ISSUE(g) { const half4* pg = tagv + ((long)bz * 64 + (g)) * npix; \
        half8 hA = *(const half8*)(pg + iv0.x); \
        half8 hB = *(const half8*)(pg + iv0.z); \
        a00h = __builtin_shufflevector(hA, hA, 0, 1, 2, 3); \
        a01h = iv0.y ? a00h : __builtin_shufflevector(hA, hA, 4, 5, 6, 7); \
        a10h = __builtin_shufflevector(hB, hB, 0, 1, 2, 3); \
        a11h = iv0.y ? a10h : __builtin_shufflevector(hB, hB, 4, 5, 6, 7); \
        if (has1) { \
            half8 hC = *(const half8*)(pg + iv1.x); \
            half8 hD = *(const half8*)(pg + iv1.z); \
            b00h = __builtin_shufflevector(hC, hC, 0, 1, 2, 3); \
            b01h = iv1.y ? b00h : __builtin_shufflevector(hC, hC, 4, 5, 6, 7); \
            b10h = __builtin_shufflevector(hD, hD, 0, 1, 2, 3); \
            b11h = iv1.y ? b10h : __builtin_shufflevector(hD, hD, 4, 5, 6, 7); } }
    #define WRITEBUF(nb) { \
        sbuf[nb][ty0][tx0] = a00h * w00h0 + a01h * w01h0 + a10h * w10h0 + a11h * w11h0; \
        if (has1) sbuf[nb][ty1][tx1] = b00h * w00h1 + b01h * w01h1 + b10h * w10h1 + b11h * w11h1; }
    #define XLOAD(c) { const float* xbc = x + (long)(bz * 64 + (c)) * 16384; \
        _Pragma("unroll") \
        for (int q = 0; q < 5; q++) { int p = tid + q * 256; float v = 0.f; \
            if (p < 1156) { int r = p / 34, qq = p % 34; \
                int y = yy0 - 1 + r, xg = xx0 - 1 + qq; \
                if ((unsigned)y < 128u && (unsigned)xg < 128u) v = xbc[y * 128 + xg]; } \
            xr[q] = v; } }
    #define XWRITE(nb) { _Pragma("unroll") \
        for (int q = 0; q < 5; q++) { int p = tid + q * 256; \
            if (p < 1156) xs[nb][p / 34][p % 34] = xr[q]; } }
    int ti = tid >> 4, tj = tid & 15;
    int i = i0 + ti, j = j0 + tj;
    long t1base = ((long)(bz * 64)) * 1024 + (long)(i >> 1) * 32 + (j >> 1);
    ISSUE(g0);
    XLOAD(g0);
    half4 dcur_h = tagp1v[t1base + (long)g0 * 1024];
    WRITEBUF(0);
    XWRITE(0);
    __syncthreads();
    int yy = 2 * i, xx = 2 * j;
    float sr = (i & 1) ? -1.f : 1.f;
    float sc = (j & 1) ? -1.f : 1.f;
    int a = 2 * ti, bq = 2 * tj;
    #pragma unroll
    for (int gg = 0; gg < GPB; gg++) {
        const int cur = gg & 1;
        half4 dnx_h;
        if (gg + 1 < GPB) {
            ISSUE(g0 + gg + 1);
            XLOAD(g0 + gg + 1);
            dnx_h = tagp1v[t1base + (long)(g0 + gg + 1) * 1024];
        }
        float4 d = to_f4(dcur_h);
        half4 acch = { (_Float16)0, (_Float16)0, (_Float16)0, (_Float16)0 };
        #pragma unroll
        for (int di = 0; di < 3; di++)
            #pragma unroll
            for (int dj = 0; dj < 3; dj++)
                acch = sbuf[cur][ti + di][tj + dj] * dwWh[gg][di * 3 + dj] + acch;
        float4 accf = to_f4(acch);
        float r0 = fmaxf(accf.x, 0.f), r1 = fmaxf(accf.y, 0.f);
        float r2 = fmaxf(accf.z, 0.f), r3 = fmaxf(accf.w, 0.f);
        float4 o;
        o.x = (r0 * pwW[gg][0]  + r1 * pwW[gg][1]  + r2 * pwW[gg][2]  + r3 * pwW[gg][3])  * wscW[gg][0];
        o.y = (r0 * pwW[gg][4]  + r1 * pwW[gg][5]  + r2 * pwW[gg][6]  + r3 * pwW[gg][7])  * wscW[gg][1];
        o.z = (r0 * pwW[gg][8]  + r1 * pwW[gg][9]  + r2 * pwW[gg][10] + r3 * pwW[gg][11]) * wscW[gg][2];
        o.w = (r0 * pwW[gg][12] + r1 * pwW[gg][13] + r2 * pwW[gg][14] + r3 * pwW[gg][15]) * wscW[gg][3];
        float nv = 0.5f * (d.x + sr * d.y + sc * d.z + sr * sc * d.w);
        float c0 = o.x + nv;
        float c1 = o.y, c2 = o.z, c3 = o.w;
        float rec00 = 0.5f * (c0 + c1 + c2 + c3);
        float rec01 = 0.5f * (c0 + c1 - c2 - c3);
        float rec10 = 0.5f * (c0 - c1 + c2 - c3);
        float rec11 = 0.5f * (c0 - c1 - c2 + c3);
        float bias = bbW[gg], scale = bsW[gg];
        float w0 = bwW[gg][0], w1 = bwW[gg][1], w2 = bwW[gg][2];
        float w3 = bwW[gg][3], w4 = bwW[gg][4], w5 = bwW[gg][5];
        float w6 = bwW[gg][6], w7 = bwW[gg][7], w8 = bwW[gg][8];
        float xv[4][4];
        #pragma unroll
        for (int r = 0; r < 4; r++) {
            float2 lo = *(const float2*)&xs[cur][a + r][bq];
            float2 hi = *(const float2*)&xs[cur][a + r][bq + 2];
            xv[r][0] = lo.x; xv[r][1] = lo.y; xv[r][2] = hi.x; xv[r][3] = hi.y;
        }
        #define CONV(dy,dx) ({ \
            float accc = bias; \
            accc = fmaf(xv[dy+0][dx+0], w0, accc); \
            accc = fmaf(xv[dy+0][dx+1], w1, accc); \
            accc = fmaf(xv[dy+0][dx+2], w2, accc); \
            accc = fmaf(xv[dy+1][dx+0], w3, accc); \
            accc = fmaf(xv[dy+1][dx+1], w4, accc); \
            accc = fmaf(xv[dy+1][dx+2], w5, accc); \
            accc = fmaf(xv[dy+2][dx+0], w6, accc); \
            accc = fmaf(xv[dy+2][dx+1], w7, accc); \
            accc = fmaf(xv[dy+2][dx+2], w8, accc); \
            accc; })
        float o00 = scale * CONV(0,0) + rec00;
        float o01 = scale * CONV(0,1) + rec01;
        float o10 = scale * CONV(1,0) + rec10;
        float o11 = scale * CONV(1,1) + rec11;
        #undef CONV
        float* ob = out + (((long)(bz * 64 + g0 + gg) * 128) + yy) * 128 + xx;
        *(float2*)ob         = make_float2(o00, o01);
        *(float2*)(ob + 128) = make_float2(o10, o11);
        if (gg + 1 < GPB) {
            dcur_h = dnx_h;
            WRITEBUF(cur ^ 1);
            XWRITE(cur ^ 1);
            __syncthreads();
        }
    }
    #undef ISSUE
    #undef WRITEBUF
    #undef XLOAD
    #undef XWRITE
}

// ---------------- launch ----------------
extern "C" void kernel_launch(void* const* d_in, const int* in_sizes, int n_in,
                              void* d_out, int out_size, void* d_ws, size_t ws_size,
                              hipStream_t stream) {
    const float* x     = (const float*)d_in[0];
    const float* bw    = (const float*)d_in[1];
    const float* bb    = (const float*)d_in[2];
    const float* bs    = (const float*)d_in[3];
    const float* offw0 = (const float*)d_in[4];
    const float* offb0 = (const float*)d_in[5];
    const float* dww0  = (const float*)d_in[6];
    const float* pww0  = (const float*)d_in[7];
    const float* wsc0  = (const float*)d_in[8];
    const float* offw1 = (const float*)d_in[9];
    const float* offb1 = (const float*)d_in[10];
    const float* dww1  = (const float*)d_in[11];
    const float* pww1  = (const float*)d_in[12];
    const float* wsc1  = (const float*)d_in[13];
    float* out = (float*)d_out;
    float* ws = (float*)d_ws;

    // workspace layout (float offsets)
    half4*     tag0h  = (half4*)(ws + 0L);
    half4*     tag1h  = (half4*)(ws + 8388608L);
    half4*     tagp1h = (half4*)(ws + 10485760L);
    _Float16*  part0h = (_Float16*)(ws + 12582912L);
    _Float16*  part1h = (_Float16*)(ws + 13631488L);
    float* avgw = ws + 13893632L;
    float* avgb = ws + 13902848L;
    float* ox0  = ws + 13902852L;
    float* oy0  = ws + 13968388L;
    float* ox1  = ws + 14033924L;
    float* oy1  = ws + 14050308L;

    k_wt01<<<4096, 256, 0, stream>>>(x, tag0h, tag1h, offw0, offb0, offw1, offb1, avgw, avgb);
    k_off_part_both<<<dim3(20, 16, 16), 256, 0, stream>>>(tag0h, tag1h, avgw, part0h, part1h);
    k_off_red_both<<<320, 256, 0, stream>>>(part0h, part1h, avgb, ox0, oy0, ox1, oy1);
    k_snake<4><<<dim3(4, 16, 16), 256, 0, stream>>>(tag1h, ox1, oy1, dww1, pww1, wsc1,
                                                    tagp1h, 16, 32, 32);
    k_snake_final<<<dim3(16, 8, 16), 256, 0, stream>>>(
        tag0h, tagp1h, ox0, oy0, dww0, pww0, wsc0,
        x, bw, bb, bs, out);
}